// Round 10
// baseline (259.809 us; speedup 1.0000x reference)
//
#include <hip/hip_runtime.h>
#include <hip/hip_bf16.h>

// CrossAttentionHead: B=8, S=2048, E=768, H=128. fp32 inputs AND fp32 output.
// q=x@Wq+bq; k=x@Wk+bk; v=x@Wv+bv; out = softmax(q k^T / sqrt(768)) @ v
// enc_output (d_in[1]) unused. Intermediates bf16, accum fp32.
// R17: cores reverted to best-measured R15 (qkv=R10 depth-1, flash=KVB32
//      depth-1; R16's depth-2 counted-vmcnt was neutral->the stall is not the
//      barrier drain; occupancy/depth/granularity all exhausted at ~38us each).
//      Change: combine_kernel ELIMINATED — folded into flash via
//      last-block-wins: counter per (qtile,b) in ws, zeroed by qkv block(0,0)
//      (runs before flash on the stream); each flash block threadfence+
//      atomicAdd after its Opart/Lpart stores; 4th arrival normalizes the
//      128 q-rows to out. Saves a dispatch + gap, overlaps 64MB combine
//      traffic with remaining flash compute.

typedef __bf16 bf16x8 __attribute__((ext_vector_type(8)));
typedef float f32x4 __attribute__((ext_vector_type(4)));
using bf16 = __hip_bfloat16;

#define EMB 768
#define HD 128
#define SEQ 2048
#define BATCH 8
#define ROWS (BATCH * SEQ)   // 16384
#define NSPLIT 4
#define KVB 32
#define TILES_PER_SPLIT (SEQ / KVB / NSPLIT)  // 16
#define NQT (SEQ / 128)      // 16 q-tiles

// ---------------------------------------------------------------- W transpose
__global__ __launch_bounds__(256) void wt_kernel(
    const float* __restrict__ Wq, const float* __restrict__ Wk,
    const float* __restrict__ Wv, bf16* __restrict__ Wt)
{
    __shared__ float t_lds[32][33];
    const int tid = threadIdx.x;
    const int k0 = blockIdx.x * 32;
    const int n0 = blockIdx.y * 32;
    const int mtx = blockIdx.z;
    const float* W = (mtx == 0) ? Wq : (mtx == 1) ? Wk : Wv;
    const int j = tid & 31, i0 = tid >> 5;
#pragma unroll
    for (int c = 0; c < 4; ++c)
        t_lds[i0 + 8 * c][j] = W[(size_t)(k0 + i0 + 8 * c) * HD + n0 + j];
    __syncthreads();
#pragma unroll
    for (int c = 0; c < 4; ++c)
        Wt[(size_t)mtx * HD * EMB + (size_t)(n0 + i0 + 8 * c) * EMB + k0 + j] =
            __float2bfloat16(t_lds[j][i0 + 8 * c]);
}

// ---------------------------------------------------------------- QKV GEMM (R10, proven)
// grid (256 row-tiles, 3 sel), block 256 (4 waves). Tile 64(M)x128(N), BK=64.
// Also zeroes the 128 flash combine-counters (block (0,0); stream-ordered
// before flash, and re-runs every iteration so ws poison is overwritten).
__global__ __launch_bounds__(256, 3) void qkv_kernel(
    const float* __restrict__ x, const bf16* __restrict__ Wt,
    const float* __restrict__ bq, const float* __restrict__ bk,
    const float* __restrict__ bv,
    bf16* __restrict__ Q, bf16* __restrict__ K, bf16* __restrict__ Vt,
    int* __restrict__ cnt)
{
    __shared__ alignas(16) bf16 b_lds[2][128 * 64];   // 32 KB, linear + XOR-swizzled
    const int tid  = threadIdx.x;
    const int sel  = blockIdx.y;
    const int row0 = blockIdx.x * 64;
    const int lane = tid & 63, wave = tid >> 6;
    const int lr = lane & 15, lq = lane >> 4;

    if (blockIdx.x == 0 && sel == 0 && tid < BATCH * NQT) cnt[tid] = 0;

    const char* Wb = (const char*)(Wt + (size_t)sel * HD * EMB);
    const int rl = lane >> 3;            // row within 8-row staging group
    const int chlog = (lane & 7) ^ rl;   // pre-swizzled source chunk

    // A: lane owns x row (row0 + wave*16 + lr), 32B at col (kt*64 + ks*32 + lq*8)
    const float* arow = &x[(size_t)(row0 + wave * 16 + lr) * EMB + lq * 8];

    float4 araw[2][2];
    auto loadA = [&](int kt) {
#pragma unroll
        for (int ks = 0; ks < 2; ++ks) {
            const float* p = arow + kt * 64 + ks * 32;
            araw[ks][0] = *reinterpret_cast<const float4*>(p);
            araw[ks][1] = *reinterpret_cast<const float4*>(p + 4);
        }
    };
    auto stageB = [&](int kt, int pb) {
#pragma unroll
        for (int c = 0; c < 4; ++c) {
            int r = c * 32 + wave * 8 + rl;
            const char* src = Wb + (size_t)r * (EMB * 2) + kt * 128 + chlog * 16;
            bf16* dst = &b_lds[pb][(size_t)(c * 32 + wave * 8) * 64]; // HW adds lane*16B
            __builtin_amdgcn_global_load_lds(
                (const __attribute__((address_space(1))) void*)src,
                (__attribute__((address_space(3))) void*)dst, 16, 0, 0);
        }
    };

    f32x4 acc[8];
#pragma unroll
    for (int j = 0; j < 8; ++j) acc[j] = f32x4{0.f, 0.f, 0.f, 0.f};

    stageB(0, 0);
    loadA(0);
    __syncthreads();                      // tile0 B in LDS, A(0) in regs

    for (int kt = 0; kt < EMB / 64; ++kt) {
        const int p = kt & 1;
        if (kt < 11) stageB(kt + 1, p ^ 1);   // issue next B tile (async, in flight)
        // cvt this tile's A (already drained by previous barrier's vmcnt(0))
        bf16x8 af[2];
#pragma unroll
        for (int ks = 0; ks < 2; ++ks) {
            union { bf16 h[8]; bf16x8 v; } u;
            u.h[0] = __float2bfloat16(araw[ks][0].x);
            u.h[1] = __float2bfloat16(araw[ks][0].y);
            u.h[2] = __float2bfloat16(araw[ks][0].z);
            u.h[3] = __float2bfloat16(araw[ks][0].w);
            u.h[4] = __float2bfloat16(araw[ks][1].x);
            u.h[5] = __float2bfloat16(araw[ks][1].y);
            u.h[6] = __float2bfloat16(araw[ks][1].z);
            u.h[7] = __float2bfloat16(araw[ks][1].w);
            af[ks] = u.v;
        }
        if (kt < 11) loadA(kt + 1);           // issue next A (regs free after cvt)
#pragma unroll
        for (int ks = 0; ks < 2; ++ks)
#pragma unroll
            for (int nt = 0; nt < 8; ++nt) {
                const bf16x8 b = *reinterpret_cast<const bf16x8*>(
                    &b_lds[p][((nt * 16 + lr) * 8 + ((ks * 4 + lq) ^ (lr & 7))) * 8]);
                acc[nt] = __builtin_amdgcn_mfma_f32_16x16x32_bf16(af[ks], b, acc[nt], 0, 0, 0);
            }
        __syncthreads();   // vmcnt(0)+lgkmcnt(0)+barrier: next tile ready, buf reusable
    }

    // epilogue: bias + transpose-store via LDS (aliases b_lds, safe after barrier)
    bf16 (*o_lds)[132] = reinterpret_cast<bf16(*)[132]>(&b_lds[0][0]);
    const float* bias = (sel == 0) ? bq : (sel == 1) ? bk : bv;
#pragma unroll
    for (int nt = 0; nt < 8; ++nt) {
        int col = nt * 16 + lr;
        float bb = bias[col];
#pragma unroll
        for (int rg = 0; rg < 4; ++rg)
            o_lds[wave * 16 + lq * 4 + rg][col] = __float2bfloat16(acc[nt][rg] + bb);
    }
    __syncthreads();
    if (sel < 2) {
        bf16* dst = (sel == 0) ? Q : K;
#pragma unroll
        for (int c = 0; c < 4; ++c) {
            int lin = tid + c * 256;
            int r = lin >> 4, ch = lin & 15;
            *reinterpret_cast<uint4*>(&dst[(size_t)(row0 + r) * HD + ch * 8]) =
                *reinterpret_cast<const uint4*>(&o_lds[r][ch * 8]);
        }
    } else {
        int d = tid >> 1, sh = (tid & 1) * 32;
        int bi = row0 >> 11, s0 = row0 & (SEQ - 1);
        union { bf16 h[32]; uint4 u4[4]; } pk;
#pragma unroll
        for (int s = 0; s < 32; ++s) pk.h[s] = o_lds[sh + s][d];
        bf16* base = &Vt[((size_t)bi * HD + d) * SEQ + s0 + sh];
#pragma unroll
        for (int c = 0; c < 4; ++c)
            *reinterpret_cast<uint4*>(base + c * 8) = pk.u4[c];
    }
}

// ---------------------------------------------------------------- flash attn (R15 core + fused combine)
// grid (16 q-tiles, 8 batches, 4 splits) = 512 blocks; block 256 = 4 waves x
// 32 q-rows. KV tile = 32 rows, double-buffered via global_load_lds
// (K swizzle r&7; V^T/P swizzle (r>>1)&3 for 64B-stride rows). One
// __syncthreads per tile. After Opart/Lpart stores: threadfence + atomicAdd
// on cnt[(b,qtile)]; the 4th-arriving split-block normalizes these 128 rows
// to out (replaces combine_kernel).
__global__ __launch_bounds__(256, 2) void flash_kernel(
    const bf16* __restrict__ Q, const bf16* __restrict__ K,
    const bf16* __restrict__ Vt,
    float* __restrict__ Opart, float* __restrict__ Lpart,
    int* __restrict__ cnt, float* __restrict__ out)
{
    __shared__ alignas(16) bf16 k_lds[2][32][128];   // 8 KB
    __shared__ alignas(16) bf16 v_lds[2][128][32];   // 16 KB (d-major)
    __shared__ alignas(16) bf16 p_lds[4][32][32];    // 8 KB
    __shared__ float linv[128];
    __shared__ int s_old;
    const int tid = threadIdx.x;
    const int lane = tid & 63, wave = tid >> 6;
    const int lr = lane & 15, lq = lane >> 4;
    const int b  = blockIdx.y;
    const int split = blockIdx.z;
    const int q0 = blockIdx.x * 128;
    const int qrow = b * SEQ + q0 + wave * 32;       // wave's 32-q base

    const float sc = 0.03608439182435161f * 1.44269504088896f; // 1/sqrt(768)*log2(e)

    // staging geometry (gload dst = wave-uniform base + lane*16B, linear)
    const int krl = lane >> 4, ksl = lane & 15;      // K: 4 rows/call (256B rows)
    const int vrl = lane >> 2, vsl = lane & 3;       // V: 16 rows/call (64B rows)

    auto stage = [&](int t, int pb) {
        // K tile: 32 rows x 128 d (16 chunks/row), 2 calls/wave
#pragma unroll
        for (int c = 0; c < 2; ++c) {
            int rbase = c * 16 + wave * 4;
            int r = rbase + krl;
            int ch = ksl ^ (r & 7);
            const bf16* src = &K[(size_t)(b * SEQ + t * KVB + r) * HD + ch * 8];
            bf16* dst = &k_lds[pb][rbase][0];
            __builtin_amdgcn_global_load_lds(
                (const __attribute__((address_space(1))) void*)src,
                (__attribute__((address_space(3))) void*)dst, 16, 0, 0);
        }
        // V^T tile: 128 d x 32 krow (4 chunks/row), 2 calls/wave
#pragma unroll
        for (int c = 0; c < 2; ++c) {
            int rbase = c * 64 + wave * 16;
            int r = rbase + vrl;
            int ch = vsl ^ ((r >> 1) & 3);
            const bf16* src = &Vt[((size_t)b * HD + r) * SEQ + t * KVB + ch * 8];
            bf16* dst = &v_lds[pb][rbase][0];
            __builtin_amdgcn_global_load_lds(
                (const __attribute__((address_space(1))) void*)src,
                (__attribute__((address_space(3))) void*)dst, 16, 0, 0);
        }
    };

    bf16x8 qf[2][4];                                  // 2 q-subtiles x 4 k-steps
#pragma unroll
    for (int qt = 0; qt < 2; ++qt)
#pragma unroll
        for (int ks = 0; ks < 4; ++ks)
            qf[qt][ks] = *reinterpret_cast<const bf16x8*>(
                &Q[(size_t)(qrow + qt * 16 + lr) * HD + ks * 32 + lq * 8]);

    f32x4 o[2][8];
#pragma unroll
    for (int qt = 0; qt < 2; ++qt)
#pragma unroll
        for (int d = 0; d < 8; ++d) o[qt][d] = f32x4{0.f, 0.f, 0.f, 0.f};
    float lsum[2] = {0.f, 0.f};

    const int t0 = split * TILES_PER_SPLIT, t1 = t0 + TILES_PER_SPLIT;
    stage(t0, 0);
    __syncthreads();                                  // tile0 staged

    // P addressing (stride-64B rows): row = qt*16+lr; swizzle = (lr>>1)&3
    char* prow0 = (char*)&p_lds[wave][lr][0];
    char* prow1 = (char*)&p_lds[wave][16 + lr][0];
    const int psw = (lr >> 1) & 3;

    for (int t = t0; t < t1; ++t) {
        const int pb = (t - t0) & 1;
        if (t + 1 < t1) stage(t + 1, pb ^ 1);         // async, in flight all phase

        // S^T = K q^T per k-subtile nt (2): kf loaded once, reused for 2 q-subtiles.
#pragma unroll
        for (int nt = 0; nt < 2; ++nt) {
            bf16x8 kf[4];
#pragma unroll
            for (int ks = 0; ks < 4; ++ks)
                kf[ks] = *reinterpret_cast<const bf16x8*>(
                    &k_lds[pb][nt * 16 + lr][((ks * 4 + lq) ^ (lr & 7)) * 8]);
#pragma unroll
            for (int qt = 0; qt < 2; ++qt) {
                f32x4 s = f32x4{0.f, 0.f, 0.f, 0.f};
#pragma unroll
                for (int ks = 0; ks < 4; ++ks)
                    s = __builtin_amdgcn_mfma_f32_16x16x32_bf16(kf[ks], qf[qt][ks], s, 0, 0, 0);
                union { bf16 h[4]; uint2 u; } pk;
#pragma unroll
                for (int r = 0; r < 4; ++r) {
                    float e = exp2f(__builtin_fmaf(s[r], sc, -8.0f));
                    pk.h[r] = __float2bfloat16(e);
                    lsum[qt] += __bfloat162float(pk.h[r]);   // == ones-row MFMA sum
                }
                char* prow = qt ? prow1 : prow0;
                *reinterpret_cast<uint2*>(
                    prow + (((nt * 2 + (lq >> 1)) ^ psw) << 4) + ((lq & 1) << 3)) = pk.u;
            }
        }
        // p region is wave-private: same-wave LDS write->read ordered by lgkmcnt

        // O^T += V^T P^T : single K=32 chunk per tile
        bf16x8 pf[2];
#pragma unroll
        for (int qt = 0; qt < 2; ++qt) {
            const char* prow = qt ? prow1 : prow0;
            pf[qt] = *reinterpret_cast<const bf16x8*>(prow + ((lq ^ psw) << 4));
        }
#pragma unroll
        for (int d = 0; d < 8; ++d) {
            int vr = d * 16 + lr;
            bf16x8 vf = *reinterpret_cast<const bf16x8*>(
                &v_lds[pb][vr][(lq ^ ((vr >> 1) & 3)) * 8]);
#pragma unroll
            for (int qt = 0; qt < 2; ++qt)
                o[qt][d] = __builtin_amdgcn_mfma_f32_16x16x32_bf16(vf, pf[qt], o[qt][d], 0, 0, 0);
        }
        __syncthreads();   // vmcnt(0)+lgkmcnt(0)+barrier: next tile staged, buf free
    }

    // l: reduce partial sums across the 4 lanes sharing a q-row (lq dim)
#pragma unroll
    for (int qt = 0; qt < 2; ++qt) {
        lsum[qt] += __shfl_xor(lsum[qt], 16);
        lsum[qt] += __shfl_xor(lsum[qt], 32);
    }

    // O^T frag: q = qrow+qt*16+lr, d = dtile*16 + lq*4 + reg  -> float4 stores
    const size_t obase = (size_t)split * ROWS;
#pragma unroll
    for (int qt = 0; qt < 2; ++qt) {
#pragma unroll
        for (int d = 0; d < 8; ++d)
            *reinterpret_cast<f32x4*>(
                &Opart[(obase + qrow + qt * 16 + lr) * HD + d * 16 + lq * 4]) = o[qt][d];
        if (lane < 16)                               // one lane per q-row
            Lpart[obase + qrow + qt * 16 + lr] = lsum[qt];
    }

    // ---- fused combine: 4th split-block for this (b, qtile) normalizes ----
    __threadfence();                                  // release Opart/Lpart (device scope)
    if (tid == 0) s_old = atomicAdd(&cnt[b * NQT + blockIdx.x], 1);
    __syncthreads();
    if (s_old == 3) {
        __threadfence();                              // acquire other splits' writes
        const int rbase = b * SEQ + q0;               // 128 rows of out
        for (int r = tid; r < 128; r += 256) {
            float L = 0.f;
#pragma unroll
            for (int s = 0; s < NSPLIT; ++s)
                L += Lpart[(size_t)s * ROWS + rbase + r];
            linv[r] = 1.f / L;
        }
        __syncthreads();
        for (int u = tid; u < 128 * 32; u += 256) {
            int r = u >> 5, c = u & 31;
            size_t off = (size_t)(rbase + r) * HD + c * 4;
            float4 a = {0.f, 0.f, 0.f, 0.f};
#pragma unroll
            for (int s = 0; s < NSPLIT; ++s) {
                float4 v = *reinterpret_cast<const float4*>(
                    &Opart[(size_t)s * ROWS * HD + off]);
                a.x += v.x; a.y += v.y; a.z += v.z; a.w += v.w;
            }
            float iv = linv[r];
            a.x *= iv; a.y *= iv; a.z *= iv; a.w *= iv;
            *reinterpret_cast<float4*>(&out[off]) = a;
        }
    }
}

// ---------------------------------------------------------------- launch
extern "C" void kernel_launch(void* const* d_in, const int* in_sizes, int n_in,
                              void* d_out, int out_size, void* d_ws, size_t ws_size,
                              hipStream_t stream) {
    const float* x  = (const float*)d_in[0];
    const float* Wq = (const float*)d_in[2];
    const float* bq = (const float*)d_in[3];
    const float* Wk = (const float*)d_in[4];
    const float* bk = (const float*)d_in[5];
    const float* Wv = (const float*)d_in[6];
    const float* bv = (const float*)d_in[7];
    float* out = (float*)d_out;

    char* ws = (char*)d_ws;
    const size_t WT_BYTES  = (size_t)3 * HD * EMB * 2;
    const size_t QKV_BYTES = (size_t)ROWS * HD * 2;
    const size_t OP_BYTES  = (size_t)NSPLIT * ROWS * HD * 4;
    const size_t LP_BYTES  = (size_t)NSPLIT * ROWS * 4;
    bf16*  Wt    = (bf16*)ws;
    bf16*  Qb    = (bf16*)(ws + WT_BYTES);
    bf16*  Kb    = (bf16*)(ws + WT_BYTES + QKV_BYTES);
    bf16*  Vt    = (bf16*)(ws + WT_BYTES + 2 * QKV_BYTES);
    float* Opart = (float*)(ws + WT_BYTES + 3 * QKV_BYTES);
    float* Lpart = (float*)(ws + WT_BYTES + 3 * QKV_BYTES + OP_BYTES);
    int*   cnt   = (int*)  (ws + WT_BYTES + 3 * QKV_BYTES + OP_BYTES + LP_BYTES);

    hipLaunchKernelGGL(wt_kernel, dim3(EMB / 32, HD / 32, 3), dim3(256), 0, stream,
                       Wq, Wk, Wv, Wt);
    hipLaunchKernelGGL(qkv_kernel, dim3(ROWS / 64, 3), dim3(256), 0, stream,
                       x, Wt, bq, bk, bv, Qb, Kb, Vt, cnt);
    hipLaunchKernelGGL(flash_kernel, dim3(NQT, BATCH, NSPLIT), dim3(256), 0, stream,
                       Qb, Kb, Vt, Opart, Lpart, cnt, out);
}

// Round 11
// 181.531 us; speedup vs baseline: 1.4312x; 1.4312x over previous
//
#include <hip/hip_runtime.h>
#include <hip/hip_bf16.h>

// CrossAttentionHead: B=8, S=2048, E=768, H=128. fp32 inputs AND fp32 output.
// q=x@Wq+bq; k=x@Wk+bk; v=x@Wv+bv; out = softmax(q k^T / sqrt(768)) @ v
// enc_output (d_in[1]) unused. Intermediates bf16, accum fp32.
// R18: exact revert to R10 — the session's best (182.1us). Post-R10 ledger:
//      R11 fused-QKV (-occ) 183.8; R13 2x4w blocks 184.3; R14 forced-occ
//      spill 230; R15 KVB32 185.7; R16 depth-2 counted-vmcnt NULL 189;
//      R17 fused-combine via per-block __threadfence 259 (device-scope
//      fence on non-coherent XCD L2s = L2 writeback per block — NEVER
//      fence per-block on CDNA4; cross-kernel handoff through L2 is cheap).
//      Remaining budget: 2x256MiB harness poison fills (~82us, fixed) +
//      qkv ~38 + flash ~39 + combine ~8 + wt ~2: every occupancy/depth/
//      granularity/swizzle/fusion lever tested neutral at this floor.

typedef __bf16 bf16x8 __attribute__((ext_vector_type(8)));
typedef float f32x4 __attribute__((ext_vector_type(4)));
using bf16 = __hip_bfloat16;

#define EMB 768
#define HD 128
#define SEQ 2048
#define BATCH 8
#define ROWS (BATCH * SEQ)   // 16384
#define NSPLIT 4
#define TILES_PER_SPLIT (SEQ / 64 / NSPLIT)  // 8

// ---------------------------------------------------------------- W transpose
__global__ __launch_bounds__(256) void wt_kernel(
    const float* __restrict__ Wq, const float* __restrict__ Wk,
    const float* __restrict__ Wv, bf16* __restrict__ Wt)
{
    __shared__ float t_lds[32][33];
    const int tid = threadIdx.x;
    const int k0 = blockIdx.x * 32;
    const int n0 = blockIdx.y * 32;
    const int mtx = blockIdx.z;
    const float* W = (mtx == 0) ? Wq : (mtx == 1) ? Wk : Wv;
    const int j = tid & 31, i0 = tid >> 5;
#pragma unroll
    for (int c = 0; c < 4; ++c)
        t_lds[i0 + 8 * c][j] = W[(size_t)(k0 + i0 + 8 * c) * HD + n0 + j];
    __syncthreads();
#pragma unroll
    for (int c = 0; c < 4; ++c)
        Wt[(size_t)mtx * HD * EMB + (size_t)(n0 + i0 + 8 * c) * EMB + k0 + j] =
            __float2bfloat16(t_lds[j][i0 + 8 * c]);
}

// ---------------------------------------------------------------- QKV GEMM (R10)
// grid (256 row-tiles, 3 sel), block 256 (4 waves). Tile 64(M)x128(N), BK=64.
// B tile in LDS: [128 rows][8 slots of 16B], slot s of row r holds logical
// 16B-chunk s^(r&7). Written linearly by global_load_lds (lane l of the
// 8-row group -> row base+(l>>3), slot l&7, source chunk (l&7)^(l>>3)).
__global__ __launch_bounds__(256, 3) void qkv_kernel(
    const float* __restrict__ x, const bf16* __restrict__ Wt,
    const float* __restrict__ bq, const float* __restrict__ bk,
    const float* __restrict__ bv,
    bf16* __restrict__ Q, bf16* __restrict__ K, bf16* __restrict__ Vt)
{
    __shared__ alignas(16) bf16 b_lds[2][128 * 64];   // 32 KB, linear + XOR-swizzled
    const int tid  = threadIdx.x;
    const int sel  = blockIdx.y;
    const int row0 = blockIdx.x * 64;
    const int lane = tid & 63, wave = tid >> 6;
    const int lr = lane & 15, lq = lane >> 4;

    const char* Wb = (const char*)(Wt + (size_t)sel * HD * EMB);
    const int rl = lane >> 3;            // row within 8-row staging group
    const int chlog = (lane & 7) ^ rl;   // pre-swizzled source chunk

    // A: lane owns x row (row0 + wave*16 + lr), 32B at col (kt*64 + ks*32 + lq*8)
    const float* arow = &x[(size_t)(row0 + wave * 16 + lr) * EMB + lq * 8];

    float4 araw[2][2];
    auto loadA = [&](int kt) {
#pragma unroll
        for (int ks = 0; ks < 2; ++ks) {
            const float* p = arow + kt * 64 + ks * 32;
            araw[ks][0] = *reinterpret_cast<const float4*>(p);
            araw[ks][1] = *reinterpret_cast<const float4*>(p + 4);
        }
    };
    auto stageB = [&](int kt, int pb) {
#pragma unroll
        for (int c = 0; c < 4; ++c) {
            int r = c * 32 + wave * 8 + rl;
            const char* src = Wb + (size_t)r * (EMB * 2) + kt * 128 + chlog * 16;
            bf16* dst = &b_lds[pb][(size_t)(c * 32 + wave * 8) * 64]; // HW adds lane*16B
            __builtin_amdgcn_global_load_lds(
                (const __attribute__((address_space(1))) void*)src,
                (__attribute__((address_space(3))) void*)dst, 16, 0, 0);
        }
    };

    f32x4 acc[8];
#pragma unroll
    for (int j = 0; j < 8; ++j) acc[j] = f32x4{0.f, 0.f, 0.f, 0.f};

    stageB(0, 0);
    loadA(0);
    __syncthreads();                      // tile0 B in LDS, A(0) in regs

    for (int kt = 0; kt < EMB / 64; ++kt) {
        const int p = kt & 1;
        if (kt < 11) stageB(kt + 1, p ^ 1);   // issue next B tile (async, in flight)
        // cvt this tile's A (already drained by previous barrier's vmcnt(0))
        bf16x8 af[2];
#pragma unroll
        for (int ks = 0; ks < 2; ++ks) {
            union { bf16 h[8]; bf16x8 v; } u;
            u.h[0] = __float2bfloat16(araw[ks][0].x);
            u.h[1] = __float2bfloat16(araw[ks][0].y);
            u.h[2] = __float2bfloat16(araw[ks][0].z);
            u.h[3] = __float2bfloat16(araw[ks][0].w);
            u.h[4] = __float2bfloat16(araw[ks][1].x);
            u.h[5] = __float2bfloat16(araw[ks][1].y);
            u.h[6] = __float2bfloat16(araw[ks][1].z);
            u.h[7] = __float2bfloat16(araw[ks][1].w);
            af[ks] = u.v;
        }
        if (kt < 11) loadA(kt + 1);           // issue next A (regs free after cvt)
#pragma unroll
        for (int ks = 0; ks < 2; ++ks)
#pragma unroll
            for (int nt = 0; nt < 8; ++nt) {
                const bf16x8 b = *reinterpret_cast<const bf16x8*>(
                    &b_lds[p][((nt * 16 + lr) * 8 + ((ks * 4 + lq) ^ (lr & 7))) * 8]);
                acc[nt] = __builtin_amdgcn_mfma_f32_16x16x32_bf16(af[ks], b, acc[nt], 0, 0, 0);
            }
        __syncthreads();   // vmcnt(0)+lgkmcnt(0)+barrier: next tile ready, buf reusable
    }

    // epilogue: bias + transpose-store via LDS (aliases b_lds, safe after barrier)
    bf16 (*o_lds)[132] = reinterpret_cast<bf16(*)[132]>(&b_lds[0][0]);
    const float* bias = (sel == 0) ? bq : (sel == 1) ? bk : bv;
#pragma unroll
    for (int nt = 0; nt < 8; ++nt) {
        int col = nt * 16 + lr;
        float bb = bias[col];
#pragma unroll
        for (int rg = 0; rg < 4; ++rg)
            o_lds[wave * 16 + lq * 4 + rg][col] = __float2bfloat16(acc[nt][rg] + bb);
    }
    __syncthreads();
    if (sel < 2) {
        bf16* dst = (sel == 0) ? Q : K;
#pragma unroll
        for (int c = 0; c < 4; ++c) {
            int lin = tid + c * 256;
            int r = lin >> 4, ch = lin & 15;
            *reinterpret_cast<uint4*>(&dst[(size_t)(row0 + r) * HD + ch * 8]) =
                *reinterpret_cast<const uint4*>(&o_lds[r][ch * 8]);
        }
    } else {
        int d = tid >> 1, sh = (tid & 1) * 32;
        int bi = row0 >> 11, s0 = row0 & (SEQ - 1);
        union { bf16 h[32]; uint4 u4[4]; } pk;
#pragma unroll
        for (int s = 0; s < 32; ++s) pk.h[s] = o_lds[sh + s][d];
        bf16* base = &Vt[((size_t)bi * HD + d) * SEQ + s0 + sh];
#pragma unroll
        for (int c = 0; c < 4; ++c)
            *reinterpret_cast<uint4*>(base + c * 8) = pk.u4[c];
    }
}

// ---------------------------------------------------------------- flash attn (split-K, S^T, 32q/wave)
// grid (16 q-tiles, 8 batches, 4 splits) = 512 blocks; block 256 = 4 waves x 32 q.
// S^T = K q^T (fixed-shift exp2), O^T = V^T P^T; l via ones-row at d=128.
// kf/vf LDS fragments reused across 2 q-subtiles from registers.
__global__ __launch_bounds__(256, 2) void flash_kernel(
    const bf16* __restrict__ Q, const bf16* __restrict__ K,
    const bf16* __restrict__ Vt,
    float* __restrict__ Opart, float* __restrict__ Lpart)
{
    __shared__ alignas(16) bf16 k_lds[64][132];      // [krow][d]      16.9 KB
    __shared__ alignas(16) bf16 v_lds[144][68];      // [d][krow]+ones 19.6 KB
    __shared__ alignas(16) bf16 p_lds[4][32][72];    // per-wave P^T   18.4 KB
    const int tid = threadIdx.x;
    const int lane = tid & 63, wave = tid >> 6;
    const int lr = lane & 15, lq = lane >> 4;
    const int b  = blockIdx.y;
    const int split = blockIdx.z;
    const int q0 = blockIdx.x * 128;
    const int qrow = b * SEQ + q0 + wave * 32;       // wave's 32-q base

    const float sc = 0.03608439182435161f * 1.44269504088896f; // 1/sqrt(768)*log2(e)

    // ones-row block for l: v_lds row 128 = 1.0, rows 129..143 = 0 (written once)
    for (int i = tid; i < 16 * 68; i += 256) {
        int r = i / 68, c = i % 68;
        v_lds[128 + r][c] = __float2bfloat16(r == 0 ? 1.0f : 0.0f);
    }

    bf16x8 qf[2][4];                                  // 2 q-subtiles x 4 k-steps
#pragma unroll
    for (int qt = 0; qt < 2; ++qt)
#pragma unroll
        for (int ks = 0; ks < 4; ++ks)
            qf[qt][ks] = *reinterpret_cast<const bf16x8*>(
                &Q[(size_t)(qrow + qt * 16 + lr) * HD + ks * 32 + lq * 8]);

    f32x4 o[2][9];
#pragma unroll
    for (int qt = 0; qt < 2; ++qt)
#pragma unroll
        for (int d = 0; d < 9; ++d) o[qt][d] = f32x4{0.f, 0.f, 0.f, 0.f};

    for (int t = split * TILES_PER_SPLIT; t < (split + 1) * TILES_PER_SPLIT; ++t) {
        __syncthreads();                             // prev iter's LDS reads done (covers init)
#pragma unroll
        for (int c = 0; c < 4; ++c) {                // K tile: 64 rows x 128 d
            int lin = tid + c * 256;
            int r = lin >> 4, ch = lin & 15;
            *reinterpret_cast<uint4*>(&k_lds[r][ch * 8]) =
                *reinterpret_cast<const uint4*>(&K[(size_t)(b * SEQ + t * 64 + r) * HD + ch * 8]);
        }
#pragma unroll
        for (int c = 0; c < 4; ++c) {                // Vt tile: 128 d x 64 krow
            int lin = tid + c * 256;
            int r = lin >> 3, ch = lin & 7;
            *reinterpret_cast<uint4*>(&v_lds[r][ch * 8]) =
                *reinterpret_cast<const uint4*>(&Vt[((size_t)b * HD + r) * SEQ + t * 64 + ch * 8]);
        }
        __syncthreads();

        // S^T per k-subtile nt: kf loaded once, reused for both q-subtiles.
        // s layout: lane holds q = qt*16+lr, k = nt*16+lq*4+r
#pragma unroll
        for (int nt = 0; nt < 4; ++nt) {
            bf16x8 kf[4];
#pragma unroll
            for (int ks = 0; ks < 4; ++ks)
                kf[ks] = *reinterpret_cast<const bf16x8*>(&k_lds[nt * 16 + lr][ks * 32 + lq * 8]);
#pragma unroll
            for (int qt = 0; qt < 2; ++qt) {
                f32x4 s = f32x4{0.f, 0.f, 0.f, 0.f};
#pragma unroll
                for (int ks = 0; ks < 4; ++ks)
                    s = __builtin_amdgcn_mfma_f32_16x16x32_bf16(kf[ks], qf[qt][ks], s, 0, 0, 0);
                union { bf16 h[4]; uint2 u; } pk;
#pragma unroll
                for (int r = 0; r < 4; ++r)
                    pk.h[r] = __float2bfloat16(exp2f(__builtin_fmaf(s[r], sc, -8.0f)));
                *reinterpret_cast<uint2*>(&p_lds[wave][qt * 16 + lr][nt * 16 + lq * 4]) = pk.u;
            }
        }
        // wave-private p region: no barrier needed

        // O^T += V^T P^T : vf loaded once per (d,ks), reused for both q-subtiles
#pragma unroll
        for (int ks = 0; ks < 2; ++ks) {
            bf16x8 pf[2];
#pragma unroll
            for (int qt = 0; qt < 2; ++qt)
                pf[qt] = *reinterpret_cast<const bf16x8*>(
                    &p_lds[wave][qt * 16 + lr][ks * 32 + lq * 8]);
#pragma unroll
            for (int d = 0; d < 9; ++d) {
                bf16x8 vf = *reinterpret_cast<const bf16x8*>(&v_lds[d * 16 + lr][ks * 32 + lq * 8]);
#pragma unroll
                for (int qt = 0; qt < 2; ++qt)
                    o[qt][d] = __builtin_amdgcn_mfma_f32_16x16x32_bf16(vf, pf[qt], o[qt][d], 0, 0, 0);
            }
        }
    }

    // O^T frag: q = qrow+qt*16+lr, d = dtile*16 + lq*4 + reg  -> float4 stores
    const size_t obase = (size_t)split * ROWS;
#pragma unroll
    for (int qt = 0; qt < 2; ++qt) {
#pragma unroll
        for (int d = 0; d < 8; ++d)
            *reinterpret_cast<f32x4*>(
                &Opart[(obase + qrow + qt * 16 + lr) * HD + d * 16 + lq * 4]) = o[qt][d];
        if (lane < 16)                               // lq==0, reg 0 of tile 8 = l(q)
            Lpart[obase + qrow + qt * 16 + lr] = o[qt][8][0];
    }
}

// ---------------------------------------------------------------- combine
__global__ __launch_bounds__(256) void combine_kernel(
    const float* __restrict__ Opart, const float* __restrict__ Lpart,
    float* __restrict__ out)
{
    int gid = blockIdx.x * 256 + threadIdx.x;      // ROWS * 32
    int row = gid >> 5, dc = gid & 31;
    float L = 0.f;
#pragma unroll
    for (int s = 0; s < NSPLIT; ++s)
        L += Lpart[(size_t)s * ROWS + row];
    float4 acc = {0.f, 0.f, 0.f, 0.f};
#pragma unroll
    for (int s = 0; s < NSPLIT; ++s) {
        float4 v = *reinterpret_cast<const float4*>(&Opart[((size_t)s * ROWS + row) * HD + dc * 4]);
        acc.x += v.x; acc.y += v.y; acc.z += v.z; acc.w += v.w;
    }
    float inv = 1.f / L;
    acc.x *= inv; acc.y *= inv; acc.z *= inv; acc.w *= inv;
    *reinterpret_cast<float4*>(&out[(size_t)row * HD + dc * 4]) = acc;
}

// ---------------------------------------------------------------- launch
extern "C" void kernel_launch(void* const* d_in, const int* in_sizes, int n_in,
                              void* d_out, int out_size, void* d_ws, size_t ws_size,
                              hipStream_t stream) {
    const float* x  = (const float*)d_in[0];
    const float* Wq = (const float*)d_in[2];
    const float* bq = (const float*)d_in[3];
    const float* Wk = (const float*)d_in[4];
    const float* bk = (const float*)d_in[5];
    const float* Wv = (const float*)d_in[6];
    const float* bv = (const float*)d_in[7];
    float* out = (float*)d_out;

    char* ws = (char*)d_ws;
    const size_t WT_BYTES  = (size_t)3 * HD * EMB * 2;
    const size_t QKV_BYTES = (size_t)ROWS * HD * 2;
    const size_t OP_BYTES  = (size_t)NSPLIT * ROWS * HD * 4;
    bf16*  Wt    = (bf16*)ws;
    bf16*  Qb    = (bf16*)(ws + WT_BYTES);
    bf16*  Kb    = (bf16*)(ws + WT_BYTES + QKV_BYTES);
    bf16*  Vt    = (bf16*)(ws + WT_BYTES + 2 * QKV_BYTES);
    float* Opart = (float*)(ws + WT_BYTES + 3 * QKV_BYTES);
    float* Lpart = (float*)(ws + WT_BYTES + 3 * QKV_BYTES + OP_BYTES);

    hipLaunchKernelGGL(wt_kernel, dim3(EMB / 32, HD / 32, 3), dim3(256), 0, stream,
                       Wq, Wk, Wv, Wt);
    hipLaunchKernelGGL(qkv_kernel, dim3(ROWS / 64, 3), dim3(256), 0, stream,
                       x, Wt, bq, bk, bv, Qb, Kb, Vt);
    hipLaunchKernelGGL(flash_kernel, dim3(SEQ / 128, BATCH, NSPLIT), dim3(256), 0, stream,
                       Qb, Kb, Vt, Opart, Lpart);
    hipLaunchKernelGGL(combine_kernel, dim3(ROWS * 32 / 256), dim3(256), 0, stream,
                       Opart, Lpart, out);
}